// Round 1
// baseline (1179.976 us; speedup 1.0000x reference)
//
#include <hip/hip_runtime.h>
#include <hip/hip_bf16.h>

// Problem constants (from reference)
constexpr int BS = 8, C = 128, V = 5, H = 224, W = 224, K = 2048, ND = 64;
constexpr int HW  = H * W;
constexpr int VHW = V * H * W;

// One block (128 threads = 2 waves) per sample point.
//   Phase 1: thread t gathers 4 pixels of channel t and bilinear-blends -> LDS feats[128]
//   Phase 2: h = relu(feats @ W1 + b1); 128 threads split the 128-deep dot in two halves
//   Phase 3: out = h @ W2 + b2; halves split the 64-deep dot
//   Phase 4: wave 0 butterfly-reduces sum(out^2) over its 64 lanes, normalizes, stores.
__global__ __launch_bounds__(128) void peak_node_kernel(
    const float* __restrict__ fm,   // [BS,C,V,H,W]
    const float* __restrict__ pos,  // [BS,K,3]
    const float* __restrict__ W1,   // [C,ND]
    const float* __restrict__ b1,   // [ND]
    const float* __restrict__ W2,   // [ND,ND]
    const float* __restrict__ b2,   // [ND]
    float* __restrict__ out) {      // [BS,K,ND]
  const int p    = blockIdx.x;      // point index in [0, BS*K)
  const int b    = p >> 11;         // p / K, K = 2048
  const int t    = threadIdx.x;     // 0..127
  const int d    = t & 63;
  const int half = t >> 6;

  __shared__ float feats[C];
  __shared__ float part[128];
  __shared__ float hsh[ND];

  // ---- position decode (broadcast load; all threads compute the same) ----
  const float* pp = pos + (size_t)p * 3;
  const float pv = pp[0], ry = pp[1], cx = pp[2];
  int v = (int)pv;            v  = v  < 0 ? 0 : (v  > V - 1 ? V - 1 : v);
  const float y0f = floorf(ry), x0f = floorf(cx);
  const float wy = ry - y0f,    wx = cx - x0f;
  int y0 = (int)y0f;          y0 = y0 < 0 ? 0 : (y0 > H - 1 ? H - 1 : y0);
  int y1 = y0 + 1 > H - 1 ? H - 1 : y0 + 1;
  int x0 = (int)x0f;          x0 = x0 < 0 ? 0 : (x0 > W - 1 ? W - 1 : x0);
  int x1 = x0 + 1 > W - 1 ? W - 1 : x0 + 1;

  // ---- phase 1: gather + bilinear, one channel per thread ----
  {
    const size_t base = ((size_t)b * C + t) * VHW + (size_t)v * HW;
    const float* r0 = fm + base + (size_t)y0 * W;
    const float* r1 = fm + base + (size_t)y1 * W;
    const float f00 = r0[x0], f01 = r0[x1];
    const float f10 = r1[x0], f11 = r1[x1];
    feats[t] = (1.f - wy) * ((1.f - wx) * f00 + wx * f01)
             + wy * ((1.f - wx) * f10 + wx * f11);
  }
  __syncthreads();

  // ---- phase 2: h = relu(feats @ W1 + b1), halves split channels ----
  {
    float acc = 0.f;
    const int c0 = half * 64;
    #pragma unroll
    for (int i = 0; i < 64; ++i) {
      const int c = c0 + i;
      acc = fmaf(feats[c], W1[c * ND + d], acc);  // feats: LDS broadcast, W1: coalesced
    }
    part[t] = acc;
  }
  __syncthreads();
  if (half == 0) hsh[d] = fmaxf(part[d] + part[d + 64] + b1[d], 0.f);
  __syncthreads();

  // ---- phase 3: out = h @ W2 + b2, halves split hidden dims ----
  {
    float acc = 0.f;
    const int d0 = half * 32;
    #pragma unroll
    for (int i = 0; i < 32; ++i) {
      const int dd = d0 + i;
      acc = fmaf(hsh[dd], W2[dd * ND + d], acc);
    }
    part[t] = acc;
  }
  __syncthreads();

  // ---- phase 4: normalize over ND=64 (exactly one wave) and store ----
  if (half == 0) {
    float o = part[d] + part[d + 64] + b2[d];
    float sq = o * o;
    #pragma unroll
    for (int m = 1; m < 64; m <<= 1) sq += __shfl_xor(sq, m);  // 64-lane butterfly
    const float nrm = sqrtf(sq);
    out[(size_t)p * ND + d] = o / fmaxf(nrm, 1e-12f);
  }
}

extern "C" void kernel_launch(void* const* d_in, const int* in_sizes, int n_in,
                              void* d_out, int out_size, void* d_ws, size_t ws_size,
                              hipStream_t stream) {
  const float* fm  = (const float*)d_in[0];  // feature_map [8,128,5,224,224]
  const float* pos = (const float*)d_in[1];  // peak_positions [8,2048,3]
  const float* W1  = (const float*)d_in[2];  // [128,64]
  const float* b1  = (const float*)d_in[3];  // [64]
  const float* W2  = (const float*)d_in[4];  // [64,64]
  const float* b2  = (const float*)d_in[5];  // [64]
  float* out = (float*)d_out;                // [8,2048,64]

  peak_node_kernel<<<BS * K, 128, 0, stream>>>(fm, pos, W1, b1, W2, b2, out);
}